// Round 2
// baseline (20935.356 us; speedup 1.0000x reference)
//
#include <hip/hip_runtime.h>

// Aggregator forward: 2-layer LSTM + LN + chunk pivots + expected multi-head attention.
// B=8,T=1024,F=H=FF=512,K=32,CS=32,NH=8,HD=64. Outputs f32: [8,32,512] ++ [8,32,1024].
// Precision scheme: every matmul operand kept as (hi,lo) bf16 pair; GEMMs compute
// Ah*Bh + Al*Bh + Ah*Bl (bf16x3, ~f32-accurate). LSTM c/h math in f32.

typedef unsigned short u16;
typedef __attribute__((ext_vector_type(8))) short bf16x8;
typedef __attribute__((ext_vector_type(4))) float f32x4;

#define T_    1024
#define NBLK  16

__device__ __forceinline__ float bf2f(u16 h) {
    union { unsigned int u; float f; } v; v.u = ((unsigned int)h) << 16; return v.f;
}
__device__ __forceinline__ u16 f2bf(float x) {
    union { float f; unsigned int u; } v; v.f = x;
    unsigned int r = (v.u + 0x7FFFu + ((v.u >> 16) & 1u)) >> 16;
    return (u16)r;
}
__device__ __forceinline__ float sigm(float x) { return 1.f / (1.f + __expf(-x)); }
__device__ __forceinline__ float tanhf_(float x) {
    float e = __expf(-2.f * fabsf(x));
    float t = (1.f - e) / (1.f + e);
    return x < 0.f ? -t : t;
}

// ---------------- split f32 -> (hi,lo) bf16 ----------------
__global__ __launch_bounds__(256) void k_split(const float* __restrict__ in,
                                               u16* __restrict__ hi, u16* __restrict__ lo, long n) {
    long i = ((long)blockIdx.x * 256 + threadIdx.x) * 4;
    if (i >= n) return;
    union { u16 h[4]; unsigned long long q; } ph, pl;
#pragma unroll
    for (int j = 0; j < 4; ++j) {
        float v = in[i + j];
        u16 h = f2bf(v);
        ph.h[j] = h;
        pl.h[j] = f2bf(v - bf2f(h));
    }
    *reinterpret_cast<unsigned long long*>(hi + i) = ph.q;
    *reinterpret_cast<unsigned long long*>(lo + i) = pl.q;
}

__global__ __launch_bounds__(256) void k_addvec(const float* __restrict__ a, const float* __restrict__ b,
                                                float* __restrict__ o, int n) {
    int i = blockIdx.x * 256 + threadIdx.x;
    if (i < n) o[i] = a[i] + b[i];
}

// h1 ring [(t+1)][16][512] (hi,lo) -> row-major [b*T+t][512] (hi,lo)
__global__ __launch_bounds__(256) void k_reorder(const u16* __restrict__ rh, const u16* __restrict__ rl,
                                                 u16* __restrict__ oh, u16* __restrict__ ol) {
    int flat = blockIdx.x * 256 + threadIdx.x;
    int c4 = flat & 127;
    int m  = flat >> 7;
    int b = m >> 10, t = m & 1023;
    long so = ((long)(t + 1) * 16 + b) * 512 + c4 * 4;
    long dof = (long)m * 512 + c4 * 4;
    *reinterpret_cast<unsigned long long*>(oh + dof) = *reinterpret_cast<const unsigned long long*>(rh + so);
    *reinterpret_cast<unsigned long long*>(ol + dof) = *reinterpret_cast<const unsigned long long*>(rl + so);
}

// ---------------- bf16x3 MFMA GEMM: C[M,N] = A[M,K] @ B[N,K]^T (+bias) ----------------
// 128x128 block tile, 4 waves (2x2), 4x4 16x16x32 fragments, direct global frag loads.
// Output: f32 (Cf) or split (Ch,Cl).
__global__ __launch_bounds__(256)
void k_gemm(const u16* __restrict__ Ah, const u16* __restrict__ Al,
            const u16* __restrict__ Bh, const u16* __restrict__ Bl,
            const float* __restrict__ bias,
            float* __restrict__ Cf, u16* __restrict__ Ch, u16* __restrict__ Cl,
            int M, int N, int K, long sA, long sB, long sC)
{
    const int lane = threadIdx.x & 63;
    const int wave = threadIdx.x >> 6;
    const int wr = wave >> 1, wc = wave & 1;
    const long bz = blockIdx.z;
    const u16* Ahb = Ah + bz * sA;
    const u16* Alb = Al + bz * sA;
    const u16* Bhb = Bh + bz * sB;
    const u16* Blb = Bl + bz * sB;
    const int rowBase = blockIdx.y * 128 + wr * 64;
    const int colBase = blockIdx.x * 128 + wc * 64;
    const int lr = lane & 15;
    const int lk = (lane >> 4) * 8;

    f32x4 acc[4][4];
#pragma unroll
    for (int j = 0; j < 4; ++j) {
        float bv = bias ? bias[colBase + j * 16 + lr] : 0.f;
#pragma unroll
        for (int i = 0; i < 4; ++i) acc[i][j] = (f32x4){bv, bv, bv, bv};
    }
    for (int k0 = 0; k0 < K; k0 += 32) {
        bf16x8 ah[4], al[4], bh[4], bl[4];
#pragma unroll
        for (int i = 0; i < 4; ++i) {
            long off = (long)(rowBase + i * 16 + lr) * K + k0 + lk;
            ah[i] = *reinterpret_cast<const bf16x8*>(Ahb + off);
            al[i] = *reinterpret_cast<const bf16x8*>(Alb + off);
        }
#pragma unroll
        for (int j = 0; j < 4; ++j) {
            long off = (long)(colBase + j * 16 + lr) * K + k0 + lk;
            bh[j] = *reinterpret_cast<const bf16x8*>(Bhb + off);
            bl[j] = *reinterpret_cast<const bf16x8*>(Blb + off);
        }
#pragma unroll
        for (int i = 0; i < 4; ++i)
#pragma unroll
            for (int j = 0; j < 4; ++j) {
                acc[i][j] = __builtin_amdgcn_mfma_f32_16x16x32_bf16(ah[i], bh[j], acc[i][j], 0, 0, 0);
                acc[i][j] = __builtin_amdgcn_mfma_f32_16x16x32_bf16(al[i], bh[j], acc[i][j], 0, 0, 0);
                acc[i][j] = __builtin_amdgcn_mfma_f32_16x16x32_bf16(ah[i], bl[j], acc[i][j], 0, 0, 0);
            }
    }
#pragma unroll
    for (int i = 0; i < 4; ++i) {
        int row0 = rowBase + i * 16 + (lane >> 4) * 4;
#pragma unroll
        for (int j = 0; j < 4; ++j) {
            int col = colBase + j * 16 + lr;
#pragma unroll
            for (int r = 0; r < 4; ++r) {
                int row = row0 + r;
                if (row < M) {
                    float v = acc[i][j][r];
                    long idx = bz * sC + (long)row * N + col;
                    if (Ch) {
                        u16 h = f2bf(v);
                        Ch[idx] = h;
                        Cl[idx] = f2bf(v - bf2f(h));
                    } else {
                        Cf[idx] = v;
                    }
                }
            }
        }
    }
}

// ---------------- persistent LSTM recurrence (bf16x3) ----------------
// 16 blocks x 256 thr. Block owns 32 hidden units (128 gate rows, gate-interleaved).
// Whh shard resident in registers as (hi,lo) B-fragments. h ring stored as (hi,lo).
__global__ __launch_bounds__(256, 1)
void k_lstm(const u16* __restrict__ Wh, const u16* __restrict__ Wl,
            const u16* __restrict__ xh, const u16* __restrict__ xl,
            u16* __restrict__ hh, u16* __restrict__ hl,
            unsigned int* __restrict__ bar)
{
    const int blk = blockIdx.x;
    const int lane = threadIdx.x & 63;
    const int wave = threadIdx.x >> 6;
    const int lr = lane & 15;
    const int lkh = lane >> 4;
    const int lk = lkh * 8;

    bf16x8 bfh[2][16], bfl[2][16];
    int grow[2];
#pragma unroll
    for (int c = 0; c < 2; ++c) {
        int rl = (wave * 2 + c) * 16 + lr;                 // local gate row 0..127
        grow[c] = (rl & 3) * 512 + blk * 32 + (rl >> 2);   // global gate row (g*512 + unit)
#pragma unroll
        for (int s = 0; s < 16; ++s) {
            long off = (long)grow[c] * 512 + s * 32 + lk;
            bfh[c][s] = *reinterpret_cast<const bf16x8*>(Wh + off);
            bfl[c][s] = *reinterpret_cast<const bf16x8*>(Wl + off);
        }
    }
    float cc[2][4];
#pragma unroll
    for (int c = 0; c < 2; ++c)
#pragma unroll
        for (int r = 0; r < 4; ++r) cc[c][r] = 0.f;

    const int batch0 = lkh * 4;
    const int basel = lane & ~3;

    for (int t = 0; t < T_; ++t) {
        float xgv[2][4];
#pragma unroll
        for (int c = 0; c < 2; ++c)
#pragma unroll
            for (int r = 0; r < 4; ++r) {
                int batch = batch0 + r;
                if (batch < 8) {
                    long xi = ((long)batch * T_ + t) * 2048 + grow[c];
                    xgv[c][r] = bf2f(xh[xi]) + bf2f(xl[xi]);
                } else xgv[c][r] = 0.f;
            }
        if (t > 0) {
            if (threadIdx.x == 0) {
                while (__hip_atomic_load(&bar[t - 1], __ATOMIC_RELAXED, __HIP_MEMORY_SCOPE_AGENT) < NBLK)
                    __builtin_amdgcn_s_sleep(2);
                (void)__hip_atomic_load(&bar[t - 1], __ATOMIC_ACQUIRE, __HIP_MEMORY_SCOPE_AGENT);
                __threadfence();
            }
            __syncthreads();
        }
        const u16* hh_t = hh + (long)t * 16 * 512;
        const u16* hl_t = hl + (long)t * 16 * 512;
        f32x4 acc0 = {xgv[0][0], xgv[0][1], xgv[0][2], xgv[0][3]};
        f32x4 acc1 = {xgv[1][0], xgv[1][1], xgv[1][2], xgv[1][3]};
#pragma unroll
        for (int s = 0; s < 16; ++s) {
            bf16x8 ahf = *reinterpret_cast<const bf16x8*>(hh_t + lr * 512 + s * 32 + lk);
            bf16x8 alf = *reinterpret_cast<const bf16x8*>(hl_t + lr * 512 + s * 32 + lk);
            acc0 = __builtin_amdgcn_mfma_f32_16x16x32_bf16(ahf, bfh[0][s], acc0, 0, 0, 0);
            acc1 = __builtin_amdgcn_mfma_f32_16x16x32_bf16(ahf, bfh[1][s], acc1, 0, 0, 0);
            acc0 = __builtin_amdgcn_mfma_f32_16x16x32_bf16(alf, bfh[0][s], acc0, 0, 0, 0);
            acc1 = __builtin_amdgcn_mfma_f32_16x16x32_bf16(alf, bfh[1][s], acc1, 0, 0, 0);
            acc0 = __builtin_amdgcn_mfma_f32_16x16x32_bf16(ahf, bfl[0][s], acc0, 0, 0, 0);
            acc1 = __builtin_amdgcn_mfma_f32_16x16x32_bf16(ahf, bfl[1][s], acc1, 0, 0, 0);
        }
#pragma unroll
        for (int c = 0; c < 2; ++c) {
            f32x4 av = (c == 0) ? acc0 : acc1;
            float hval[4];
#pragma unroll
            for (int r = 0; r < 4; ++r) {
                float v = av[r];
                float iv = __shfl(v, basel + 0, 64);
                float fv = __shfl(v, basel + 1, 64);
                float gv = __shfl(v, basel + 2, 64);
                float ov = __shfl(v, basel + 3, 64);
                float cn = sigm(fv) * cc[c][r] + sigm(iv) * tanhf_(gv);
                cc[c][r] = cn;
                hval[r] = sigm(ov) * tanhf_(cn);
            }
            if ((lane & 3) == 0 && lkh < 2) {   // gate-0 lane, batches 0..7
                int ul = ((wave * 2 + c) * 16 + lr) >> 2;
                long base = (long)(t + 1) * 16 * 512 + blk * 32 + ul;
#pragma unroll
                for (int r = 0; r < 4; ++r) {
                    float v = hval[r];
                    u16 hv = f2bf(v);
                    u16 lv = f2bf(v - bf2f(hv));
                    hh[base + (long)(batch0 + r) * 512] = hv;
                    hl[base + (long)(batch0 + r) * 512] = lv;
                }
            }
        }
        __syncthreads();
        if (threadIdx.x == 0) {
            __threadfence();
            __hip_atomic_fetch_add(&bar[t], 1u, __ATOMIC_RELEASE, __HIP_MEMORY_SCOPE_AGENT);
        }
    }
}

// ---------------- LayerNorm (reads h2 ring hi+lo, writes normed split) ----------------
__global__ __launch_bounds__(256)
void k_ln(const u16* __restrict__ rh, const u16* __restrict__ rl,
          const float* __restrict__ gamma, const float* __restrict__ beta,
          u16* __restrict__ nh, u16* __restrict__ nl)
{
    __shared__ float sb[8];
    int m = blockIdx.x;
    int b = m >> 10, t = m & 1023;
    long so = ((long)(t + 1) * 16 + b) * 512;
    int tid = threadIdx.x;
    float x0 = bf2f(rh[so + tid]) + bf2f(rl[so + tid]);
    float x1 = bf2f(rh[so + tid + 256]) + bf2f(rl[so + tid + 256]);
    float s = x0 + x1;
#pragma unroll
    for (int off = 32; off; off >>= 1) s += __shfl_down(s, off, 64);
    int wv = tid >> 6, ln = tid & 63;
    if (ln == 0) sb[wv] = s;
    __syncthreads();
    float mu = (sb[0] + sb[1] + sb[2] + sb[3]) * (1.f / 512.f);
    float d0 = x0 - mu, d1 = x1 - mu;
    float ss = d0 * d0 + d1 * d1;
#pragma unroll
    for (int off = 32; off; off >>= 1) ss += __shfl_down(ss, off, 64);
    if (ln == 0) sb[4 + wv] = ss;
    __syncthreads();
    float var = (sb[4] + sb[5] + sb[6] + sb[7]) * (1.f / 512.f);
    float rstd = rsqrtf(var + 1e-5f);
    float y0 = d0 * rstd * gamma[tid] + beta[tid];
    float y1 = d1 * rstd * gamma[tid + 256] + beta[tid + 256];
    long d = (long)m * 512;
    u16 h0 = f2bf(y0); nh[d + tid] = h0; nl[d + tid] = f2bf(y0 - bf2f(h0));
    u16 h1 = f2bf(y1); nh[d + tid + 256] = h1; nl[d + tid + 256] = f2bf(y1 - bf2f(h1));
}

// chunk sums in f32 from split normed, write split
__global__ __launch_bounds__(256)
void k_chunksum(const u16* __restrict__ nh, const u16* __restrict__ nl,
                u16* __restrict__ ch, u16* __restrict__ cl)
{
    int bk = blockIdx.x;
    int tid = threadIdx.x;
    long base = (long)bk * 32 * 512;
    float s0 = 0.f, s1 = 0.f;
#pragma unroll 4
    for (int i = 0; i < 32; ++i) {
        s0 += bf2f(nh[base + (long)i * 512 + tid]) + bf2f(nl[base + (long)i * 512 + tid]);
        s1 += bf2f(nh[base + (long)i * 512 + tid + 256]) + bf2f(nl[base + (long)i * 512 + tid + 256]);
    }
    long d = (long)bk * 512;
    u16 h0 = f2bf(s0); ch[d + tid] = h0; cl[d + tid] = f2bf(s0 - bf2f(h0));
    u16 h1 = f2bf(s1); ch[d + tid + 256] = h1; cl[d + tid + 256] = f2bf(s1 - bf2f(h1));
}

// eof + in_futctx_probs
__global__ __launch_bounds__(256)
void k_eof(const float* __restrict__ dp, const float* __restrict__ noise, float* __restrict__ ifp)
{
    int bk = blockIdx.x;
    int k = bk & 31;
    long base = (long)bk * 1024;
    int tid = threadIdx.x;
#pragma unroll
    for (int i = 0; i < 4; ++i) {
        int t = tid + i * 256;
        float e;
        if (t < (k + 1) * 32) e = 0.f;
        else e = sigm(dp[base + t] * 0.0441941738241592f + noise[base + t]);
        if (t == 0) ifp[base] = 1.f;
        if (t < 1023) ifp[base + t + 1] = 1.f - e;
    }
}

// expected attention, f32. Block = (b, h, kgroup of 8 pivot rows). 256 blocks.
__global__ __launch_bounds__(256)
void k_attn(const float* __restrict__ qf, const float* __restrict__ kvf,
            const float* __restrict__ ifp, u16* __restrict__ ctxh, u16* __restrict__ ctxl)
{
    int bh = blockIdx.x;
    int b = bh >> 5;
    int h = (bh >> 2) & 7;
    int kg = bh & 3;
    __shared__ float qs[8 * 64];
    __shared__ float tile[64 * 65];
    __shared__ float sc[8 * 1024];
    int tid = threadIdx.x;

    for (int i = tid; i < 512; i += 256) {
        int kq = i >> 6, d = i & 63;
        qs[i] = qf[((long)b * 32 + kg * 8 + kq) * 512 + h * 64 + d];
    }
    __syncthreads();
    for (int t0 = 0; t0 < 1024; t0 += 64) {
        for (int i = tid; i < 4096; i += 256) {
            int tt = i >> 6, d = i & 63;
            tile[tt * 65 + d] = kvf[((long)b * 1024 + t0 + tt) * 1024 + h * 64 + d];
        }
        __syncthreads();
#pragma unroll
        for (int pi = 0; pi < 2; ++pi) {
            int p = tid + pi * 256;
            int kq = p >> 6, tt = p & 63;
            float s = 0.f;
#pragma unroll 8
            for (int d = 0; d < 64; ++d) s += qs[kq * 64 + d] * tile[tt * 65 + d];
            sc[kq * 1024 + t0 + tt] = s * 0.125f;
        }
        __syncthreads();
    }
    {
        int w = tid >> 6, lane = tid & 63;
#pragma unroll
        for (int rr = 0; rr < 2; ++rr) {
            int kq = w * 2 + rr;
            float m = -1e30f;
            float vv[16];
#pragma unroll
            for (int i = 0; i < 16; ++i) {
                vv[i] = sc[kq * 1024 + lane + i * 64];
                m = fmaxf(m, vv[i]);
            }
#pragma unroll
            for (int off = 32; off; off >>= 1) m = fmaxf(m, __shfl_xor(m, off, 64));
            long ibase = ((long)b * 32 + kg * 8 + kq) * 1024;
            float sum = 0.f;
            float wv[16];
#pragma unroll
            for (int i = 0; i < 16; ++i) {
                float pv = ifp[ibase + lane + i * 64];
                float e = __expf(vv[i] - m) * pv;
                wv[i] = e; sum += e;
            }
#pragma unroll
            for (int off = 32; off; off >>= 1) sum += __shfl_xor(sum, off, 64);
            float inv = 1.f / sum;
#pragma unroll
            for (int i = 0; i < 16; ++i) sc[kq * 1024 + lane + i * 64] = wv[i] * inv;
        }
    }
    __syncthreads();
    float c0 = 0.f, c1 = 0.f;
    int kq0 = tid >> 6, d0 = tid & 63;
    int kq1 = (tid + 256) >> 6, d1 = tid & 63;
    for (int t0 = 0; t0 < 1024; t0 += 64) {
        __syncthreads();
        for (int i = tid; i < 4096; i += 256) {
            int tt = i >> 6, d = i & 63;
            tile[tt * 65 + d] = kvf[((long)b * 1024 + t0 + tt) * 1024 + 512 + h * 64 + d];
        }
        __syncthreads();
#pragma unroll 8
        for (int tt = 0; tt < 64; ++tt) {
            float a0 = sc[kq0 * 1024 + t0 + tt];
            float a1 = sc[kq1 * 1024 + t0 + tt];
            c0 += a0 * tile[tt * 65 + d0];
            c1 += a1 * tile[tt * 65 + d1];
        }
    }
    long i0 = ((long)b * 32 + kg * 8 + kq0) * 512 + h * 64 + d0;
    long i1 = ((long)b * 32 + kg * 8 + kq1) * 512 + h * 64 + d1;
    u16 h0 = f2bf(c0); ctxh[i0] = h0; ctxl[i0] = f2bf(c0 - bf2f(h0));
    u16 h1v = f2bf(c1); ctxh[i1] = h1v; ctxl[i1] = f2bf(c1 - bf2f(h1v));
}

// ---------------- launch ----------------
extern "C" void kernel_launch(void* const* d_in, const int* in_sizes, int n_in,
                              void* d_out, int out_size, void* d_ws, size_t ws_size,
                              hipStream_t stream)
{
    const float* input = (const float*)d_in[0];
    const float* noise = (const float*)d_in[3];
    const float* Wih  = (const float*)d_in[4];
    const float* Whh  = (const float*)d_in[5];
    const float* bih  = (const float*)d_in[6];
    const float* bhh  = (const float*)d_in[7];
    const float* gam  = (const float*)d_in[8];
    const float* bet  = (const float*)d_in[9];
    const float* Wcp  = (const float*)d_in[10]; const float* bcp  = (const float*)d_in[11];
    const float* Wff  = (const float*)d_in[12]; const float* bff  = (const float*)d_in[13];
    const float* Wq   = (const float*)d_in[14]; const float* bq   = (const float*)d_in[15];
    const float* Wkv  = (const float*)d_in[16]; const float* bkv  = (const float*)d_in[17];
    const float* Wout = (const float*)d_in[18]; const float* bout = (const float*)d_in[19];
    (void)in_sizes; (void)n_in; (void)out_size; (void)ws_size;

    float* out_ctx = (float*)d_out;
    float* out_ifp = (float*)d_out + 8 * 32 * 512;

    char* p = (char*)d_ws;
    auto alloc = [&](size_t bytes) { char* q = p; p += (bytes + 255) & ~(size_t)255; return q; };
    u16* Xh   = (u16*)alloc(8192ULL * 512 * 2);  u16* Xl   = (u16*)alloc(8192ULL * 512 * 2);
    u16* Wihh = (u16*)alloc(2ULL*2048*512*2);    u16* Wihl = (u16*)alloc(2ULL*2048*512*2);
    u16* Whhh = (u16*)alloc(2ULL*2048*512*2);    u16* Whhl = (u16*)alloc(2ULL*2048*512*2);
    u16* Wcph = (u16*)alloc(512ULL*512*2);       u16* Wcpl = (u16*)alloc(512ULL*512*2);
    u16* Wffh = (u16*)alloc(512ULL*512*2);       u16* Wffl = (u16*)alloc(512ULL*512*2);
    u16* Wqh  = (u16*)alloc(512ULL*512*2);       u16* Wql  = (u16*)alloc(512ULL*512*2);
    u16* Wkvh = (u16*)alloc(1024ULL*512*2);      u16* Wkvl = (u16*)alloc(1024ULL*512*2);
    u16* Wouth= (u16*)alloc(512ULL*512*2);       u16* Woutl= (u16*)alloc(512ULL*512*2);
    float* bias12 = (float*)alloc(4096ULL * 4);
    u16* xgh  = (u16*)alloc(8192ULL*2048*2);     u16* xgl  = (u16*)alloc(8192ULL*2048*2);
    u16* h1h  = (u16*)alloc(1025ULL*16*512*2);   u16* h1l  = (u16*)alloc(1025ULL*16*512*2);
    u16* h2h  = (u16*)alloc(1025ULL*16*512*2);   u16* h2l  = (u16*)alloc(1025ULL*16*512*2);
    u16* h1rmh= (u16*)alloc(8192ULL*512*2);      u16* h1rml= (u16*)alloc(8192ULL*512*2);
    u16* nh   = (u16*)alloc(8192ULL*512*2);      u16* nl   = (u16*)alloc(8192ULL*512*2);
    u16* csh  = (u16*)alloc(256ULL*512*2);       u16* csl  = (u16*)alloc(256ULL*512*2);
    u16* pivh = (u16*)alloc(512ULL*512*2);       u16* pivl = (u16*)alloc(512ULL*512*2); // padded
    u16* ffh  = (u16*)alloc(8192ULL*512*2);      u16* ffl  = (u16*)alloc(8192ULL*512*2);
    u16* ctxhb= (u16*)alloc(256ULL*512*2);       u16* ctxlb= (u16*)alloc(256ULL*512*2);
    float* qf  = (float*)alloc(256ULL*512*4);
    float* kvf = (float*)alloc(8192ULL*1024*4);
    float* dp  = (float*)alloc(8ULL*32*1024*4);
    unsigned int* bar1 = (unsigned int*)alloc(4096);
    unsigned int* bar2 = (unsigned int*)alloc(4096);

    hipMemsetAsync(bar1, 0, 4096, stream);
    hipMemsetAsync(bar2, 0, 4096, stream);
    hipMemsetAsync(h1h, 0, 16 * 512 * 2, stream);
    hipMemsetAsync(h1l, 0, 16 * 512 * 2, stream);
    hipMemsetAsync(h2h, 0, 16 * 512 * 2, stream);
    hipMemsetAsync(h2l, 0, 16 * 512 * 2, stream);

    k_split<<<4096, 256, 0, stream>>>(input, Xh, Xl, 8192L * 512);
    k_split<<<2048, 256, 0, stream>>>(Wih, Wihh, Wihl, 2L * 2048 * 512);
    k_split<<<2048, 256, 0, stream>>>(Whh, Whhh, Whhl, 2L * 2048 * 512);
    k_split<<<256, 256, 0, stream>>>(Wcp, Wcph, Wcpl, 512L * 512);
    k_split<<<256, 256, 0, stream>>>(Wff, Wffh, Wffl, 512L * 512);
    k_split<<<256, 256, 0, stream>>>(Wq, Wqh, Wql, 512L * 512);
    k_split<<<512, 256, 0, stream>>>(Wkv, Wkvh, Wkvl, 1024L * 512);
    k_split<<<256, 256, 0, stream>>>(Wout, Wouth, Woutl, 512L * 512);
    k_addvec<<<16, 256, 0, stream>>>(bih, bhh, bias12, 4096);

    // layer 1
    k_gemm<<<dim3(16, 64, 1), 256, 0, stream>>>(Xh, Xl, Wihh, Wihl, bias12,
                                                nullptr, xgh, xgl, 8192, 2048, 512, 0, 0, 0);
    k_lstm<<<NBLK, 256, 0, stream>>>(Whhh, Whhl, xgh, xgl, h1h, h1l, bar1);
    k_reorder<<<4096, 256, 0, stream>>>(h1h, h1l, h1rmh, h1rml);
    // layer 2
    k_gemm<<<dim3(16, 64, 1), 256, 0, stream>>>(h1rmh, h1rml, Wihh + 2048L*512, Wihl + 2048L*512,
                                                bias12 + 2048, nullptr, xgh, xgl, 8192, 2048, 512, 0, 0, 0);
    k_lstm<<<NBLK, 256, 0, stream>>>(Whhh + 2048L*512, Whhl + 2048L*512, xgh, xgl, h2h, h2l, bar2);

    k_ln<<<8192, 256, 0, stream>>>(h2h, h2l, gam, bet, nh, nl);
    k_chunksum<<<256, 256, 0, stream>>>(nh, nl, csh, csl);
    k_gemm<<<dim3(4, 2, 1), 256, 0, stream>>>(csh, csl, Wcph, Wcpl, bcp,
                                              nullptr, pivh, pivl, 256, 512, 512, 0, 0, 0);
    k_gemm<<<dim3(4, 2, 1), 256, 0, stream>>>(pivh, pivl, Wqh, Wql, bq,
                                              qf, nullptr, nullptr, 256, 512, 512, 0, 0, 0);
    k_gemm<<<dim3(4, 64, 1), 256, 0, stream>>>(nh, nl, Wffh, Wffl, bff,
                                               nullptr, ffh, ffl, 8192, 512, 512, 0, 0, 0);
    k_gemm<<<dim3(8, 64, 1), 256, 0, stream>>>(ffh, ffl, Wkvh, Wkvl, bkv,
                                               kvf, nullptr, nullptr, 8192, 1024, 512, 0, 0, 0);
    k_gemm<<<dim3(8, 1, 8), 256, 0, stream>>>(pivh, pivl, ffh, ffl, nullptr,
                                              dp, nullptr, nullptr, 32, 1024, 512,
                                              32L * 512, 1024L * 512, 32L * 1024);
    k_eof<<<256, 256, 0, stream>>>(dp, noise, out_ifp);
    k_attn<<<256, 256, 0, stream>>>(qf, kvf, out_ifp, ctxhb, ctxlb);
    k_gemm<<<dim3(4, 2, 1), 256, 0, stream>>>(ctxhb, ctxlb, Wouth, Woutl, bout,
                                              out_ctx, nullptr, nullptr, 256, 512, 512, 0, 0, 0);
}